// Round 1
// 423.603 us; speedup vs baseline: 1.0266x; 1.0266x over previous
//
#include <hip/hip_runtime.h>

// GCN layer: out = relu(segment_sum(edge_val * (x@W + b)[edge_col] -> edge_row))
// N=100000 nodes, E=1600000 edges, 256 -> 128 features, fp32 in/out.
//
// Round 7: kill gcn_bucket's write amplification. Old bucket scattered 8B
// int2s to globally-random cursor positions -> every write was a private
// 64B line writeback (WRITE_SIZE 103MB = E*64B, 95us). Replace with a
// two-phase counting sort into the SAME packed buffer:
//   phase A (gcn_bin):   256 coarse buckets (391 rows each). Per-block LDS
//                        histogram -> one global atomicAdd per (block,bucket)
//                        reserves a contiguous run -> writes combine in the
//                        block's own L2. Bucket bases are row_start[bk*391]
//                        (free, from the existing scan).
//   phase B (gcn_place): one block per bucket; stage the bucket's edges in
//                        LDS (read-before-write => in-place safe), then
//                        scatter to final per-row cursor positions inside the
//                        bucket's ~50KB contiguous region (single XCD L2 ->
//                        full-line writebacks).
// packed.x carries (row_local<<17)|col between phases; phase B strips it.
// Aggregate/gemm/hist/scans unchanged.

constexpr int kNodes = 100000;
constexpr int kEdges = 1600000;
constexpr int kInF   = 256;
constexpr int kOutF  = 128;
constexpr int kScanBlocks = (kNodes + 255) / 256;   // 391
constexpr int kBucketBlocks = 800;                  // 800*256*8 >= E
constexpr int kGemmBlocks = 1250;                   // 6250 tiles / 5 per block

constexpr int kNB = 256;                            // coarse buckets
constexpr int kRB = 391;                            // rows per bucket (256*391 >= N)
constexpr int kCap = 7808;                          // LDS-staged edges per bucket (62.5KB)

typedef __attribute__((ext_vector_type(8))) short short8;
typedef __attribute__((ext_vector_type(8))) unsigned short ush8;
typedef __attribute__((ext_vector_type(4))) float floatx4;

__device__ inline unsigned short f2bf_rne(float f) {
    unsigned int u = __float_as_uint(f);
    unsigned int r = u + 0x7FFFu + ((u >> 16) & 1u);
    return (unsigned short)(r >> 16);
}
__device__ inline float bf2f(unsigned short h) {
    return __uint_as_float(((unsigned int)h) << 16);
}

// ---------------------------------------------------------------------------
// GEMM: support_bf[N][128] = bf16(x[N][256] @ W[256][128] + b)  (unchanged)
// ---------------------------------------------------------------------------
__global__ __launch_bounds__(256) void gcn_gemm(const float* __restrict__ x,
                                                const float* __restrict__ W,
                                                const float* __restrict__ b,
                                                unsigned short* __restrict__ support) {
    const int lane = threadIdx.x & 63;
    const int wv   = threadIdx.x >> 6;
    const int rowl = lane & 15;
    const int quad = lane >> 4;
    const int colbase = wv * 32;

    short8 bfrag[2][8];
#pragma unroll
    for (int ct = 0; ct < 2; ++ct) {
        const int col = colbase + ct * 16 + rowl;
#pragma unroll
        for (int kc = 0; kc < 8; ++kc) {
            const int kb = kc * 32 + quad * 8;
            short8 f;
#pragma unroll
            for (int j = 0; j < 8; ++j)
                f[j] = (short)f2bf_rne(W[(size_t)(kb + j) * kOutF + col]);
            bfrag[ct][kc] = f;
        }
    }
    const float bias0 = b[colbase + rowl];
    const float bias1 = b[colbase + 16 + rowl];

    for (int tile = blockIdx.x; tile < kNodes / 16; tile += gridDim.x) {
        const int r0 = tile * 16;
        floatx4 acc0 = {0.f, 0.f, 0.f, 0.f};
        floatx4 acc1 = {0.f, 0.f, 0.f, 0.f};
        const float* xrow = x + (size_t)(r0 + rowl) * kInF + quad * 8;
#pragma unroll
        for (int kc = 0; kc < 8; ++kc) {
            const float4 v0 = *reinterpret_cast<const float4*>(xrow + kc * 32);
            const float4 v1 = *reinterpret_cast<const float4*>(xrow + kc * 32 + 4);
            short8 a;
            a[0] = (short)f2bf_rne(v0.x);
            a[1] = (short)f2bf_rne(v0.y);
            a[2] = (short)f2bf_rne(v0.z);
            a[3] = (short)f2bf_rne(v0.w);
            a[4] = (short)f2bf_rne(v1.x);
            a[5] = (short)f2bf_rne(v1.y);
            a[6] = (short)f2bf_rne(v1.z);
            a[7] = (short)f2bf_rne(v1.w);
            acc0 = __builtin_amdgcn_mfma_f32_16x16x32_bf16(a, bfrag[0][kc], acc0, 0, 0, 0);
            acc1 = __builtin_amdgcn_mfma_f32_16x16x32_bf16(a, bfrag[1][kc], acc1, 0, 0, 0);
        }
#pragma unroll
        for (int reg = 0; reg < 4; ++reg) {
            const size_t rbase = (size_t)(r0 + quad * 4 + reg) * kOutF + colbase;
            support[rbase + rowl]      = f2bf_rne(acc0[reg] + bias0);
            support[rbase + 16 + rowl] = f2bf_rne(acc1[reg] + bias1);
        }
    }
}

// ---------------------------------------------------------------------------
// CSR step 1: per-row edge counts (fire-and-forget atomics).
// ---------------------------------------------------------------------------
__global__ __launch_bounds__(256) void gcn_hist(const int* __restrict__ erow,
                                                int* __restrict__ counts) {
    const int stride = gridDim.x * blockDim.x;
    for (int e = blockIdx.x * blockDim.x + threadIdx.x; e < kEdges; e += stride)
        atomicAdd(&counts[erow[e]], 1);
}

// ---------------------------------------------------------------------------
// CSR step 2: two-level exclusive scan.
// ---------------------------------------------------------------------------
__global__ __launch_bounds__(256) void gcn_scan1(const int* __restrict__ counts,
                                                 int* __restrict__ row_start,
                                                 int* __restrict__ blockSums) {
    __shared__ int s[256];
    const int i = blockIdx.x * 256 + threadIdx.x;
    const int v = (i < kNodes) ? counts[i] : 0;
    s[threadIdx.x] = v;
    __syncthreads();
#pragma unroll
    for (int off = 1; off < 256; off <<= 1) {
        const int t = (threadIdx.x >= off) ? s[threadIdx.x - off] : 0;
        __syncthreads();
        s[threadIdx.x] += t;
        __syncthreads();
    }
    if (i < kNodes) row_start[i] = s[threadIdx.x] - v;
    if (threadIdx.x == 255) blockSums[blockIdx.x] = s[255];
}

__global__ __launch_bounds__(512) void gcn_scan2(const int* __restrict__ blockSums,
                                                 int* __restrict__ blockOffs) {
    __shared__ int s[512];
    const int v = (threadIdx.x < kScanBlocks) ? blockSums[threadIdx.x] : 0;
    s[threadIdx.x] = v;
    __syncthreads();
#pragma unroll
    for (int off = 1; off < 512; off <<= 1) {
        const int t = (threadIdx.x >= off) ? s[threadIdx.x - off] : 0;
        __syncthreads();
        s[threadIdx.x] += t;
        __syncthreads();
    }
    if (threadIdx.x < kScanBlocks) blockOffs[threadIdx.x] = s[threadIdx.x] - v;
}

__global__ __launch_bounds__(256) void gcn_scan3(int* __restrict__ row_start,
                                                 const int* __restrict__ blockOffs,
                                                 int* __restrict__ cursor,
                                                 int* __restrict__ bucket_cursor) {
    const int i = blockIdx.x * 256 + threadIdx.x;
    if (i < kNodes) {
        const int rs = row_start[i] + blockOffs[blockIdx.x];
        row_start[i] = rs;
        cursor[i]    = rs;
        if (i % kRB == 0) bucket_cursor[i / kRB] = rs;   // bucket base = row_start[bk*391]
    }
    if (i == 0) row_start[kNodes] = kEdges;
}

// ---------------------------------------------------------------------------
// Phase A: bin edges into 256 coarse buckets (391 rows each), write-combined.
// Per block: LDS hist over 256 buckets -> one global atomicAdd per
// (block,bucket) reserving a contiguous run -> per-edge write lands inside
// the block's own run (same CU/XCD, same phase -> L2 combines lines).
// packed.x = (row_local<<17) | col  (row_local<512, col<2^17). packed.y = val.
// ---------------------------------------------------------------------------
__global__ __launch_bounds__(256) void gcn_bin(const int* __restrict__ erow,
                                               const int* __restrict__ ecol,
                                               const float* __restrict__ eval,
                                               int* __restrict__ bucket_cursor,
                                               int2* __restrict__ packed) {
    __shared__ int cnt[kNB];
    __shared__ int base[kNB];
    __shared__ int rk[kNB];
    const int T   = kBucketBlocks * 256;
    const int tid = blockIdx.x * 256 + threadIdx.x;

    cnt[threadIdx.x] = 0;
    rk[threadIdx.x]  = 0;

    int bk[8], pk[8], vb[8];
    bool ok[8];
#pragma unroll
    for (int i = 0; i < 8; ++i) {
        const int e = tid + i * T;
        ok[i] = (e < kEdges);
        const int r = ok[i] ? erow[e] : 0;
        const int c = ok[i] ? ecol[e] : 0;
        const float v = ok[i] ? eval[e] : 0.f;
        const unsigned int b = (unsigned int)r / (unsigned int)kRB;  // compiler magic-div
        bk[i] = (int)b;
        pk[i] = ((r - (int)b * kRB) << 17) | c;
        vb[i] = __float_as_int(v);
    }
    __syncthreads();
#pragma unroll
    for (int i = 0; i < 8; ++i)
        if (ok[i]) atomicAdd(&cnt[bk[i]], 1);
    __syncthreads();
    const int c = cnt[threadIdx.x];
    base[threadIdx.x] = c ? atomicAdd(&bucket_cursor[threadIdx.x], c) : 0;
    __syncthreads();
#pragma unroll
    for (int i = 0; i < 8; ++i) {
        if (ok[i]) {
            const int r = atomicAdd(&rk[bk[i]], 1);
            packed[base[bk[i]] + r] = make_int2(pk[i], vb[i]);
        }
    }
}

// ---------------------------------------------------------------------------
// Phase B: per-bucket in-place placement. One block per bucket: stage the
// bucket's edges in LDS (+ register tail for the statistically-impossible
// overflow case), barrier, then scatter to final per-row cursor positions.
// All reads precede all writes -> in-place over packed is safe. Destinations
// span only this bucket's ~50KB region, written by one block -> full-line
// writebacks only.
// ---------------------------------------------------------------------------
__global__ __launch_bounds__(256) void gcn_place(const int* __restrict__ row_start,
                                                 int* __restrict__ cursor,
                                                 int2* __restrict__ packed) {
    __shared__ int2 st[kCap];
    const int bk = blockIdx.x;
    const int r0 = bk * kRB;
    const int r1 = min(r0 + kRB, kNodes);
    if (r0 >= kNodes) return;
    const int s0 = row_start[r0];
    const int s1 = row_start[r1];
    const int size   = s1 - s0;
    const int staged = min(size, kCap);

    for (int i = threadIdx.x; i < staged; i += 256)
        st[i] = packed[s0 + i];

    int2 tail[8];
    int  nt = 0;
    for (int i = kCap + threadIdx.x; i < size; i += 256)
        if (nt < 8) tail[nt++] = packed[s0 + i];

    __syncthreads();   // every edge of the bucket read before any write

    for (int i = threadIdx.x; i < staged; i += 256) {
        const int2 p  = st[i];
        const int row = r0 + (p.x >> 17);
        const int pos = atomicAdd(&cursor[row], 1);
        packed[pos] = make_int2(p.x & 0x1FFFF, p.y);
    }
#pragma unroll
    for (int t = 0; t < 8; ++t) {
        if (t < nt) {
            const int2 p  = tail[t];
            const int row = r0 + (p.x >> 17);
            const int pos = atomicAdd(&cursor[row], 1);
            packed[pos] = make_int2(p.x & 0x1FFFF, p.y);
        }
    }
}

// ---------------------------------------------------------------------------
// Aggregate + ReLU (unchanged): 16 lanes/node, bf16x8 gathers, fp32 acc.
// ---------------------------------------------------------------------------
__global__ __launch_bounds__(256) void gcn_aggregate(const int* __restrict__ row_start,
                                                     const int2* __restrict__ packed,
                                                     const unsigned short* __restrict__ support,
                                                     float* __restrict__ out) {
    const int n  = blockIdx.x * 16 + (threadIdx.x >> 4);
    const int f8 = (threadIdx.x & 15) * 8;
    if (n >= kNodes) return;
    const int s0 = row_start[n];
    const int s1 = row_start[n + 1];
    float acc[8];
#pragma unroll
    for (int j = 0; j < 8; ++j) acc[j] = 0.f;

    int i = s0;
    for (; i + 3 < s1; i += 4) {
        const int2 p0 = packed[i];
        const int2 p1 = packed[i + 1];
        const int2 p2 = packed[i + 2];
        const int2 p3 = packed[i + 3];
        const ush8 a0 = *reinterpret_cast<const ush8*>(support + (size_t)p0.x * kOutF + f8);
        const ush8 a1 = *reinterpret_cast<const ush8*>(support + (size_t)p1.x * kOutF + f8);
        const ush8 a2 = *reinterpret_cast<const ush8*>(support + (size_t)p2.x * kOutF + f8);
        const ush8 a3 = *reinterpret_cast<const ush8*>(support + (size_t)p3.x * kOutF + f8);
        const float v0 = __int_as_float(p0.y), v1 = __int_as_float(p1.y);
        const float v2 = __int_as_float(p2.y), v3 = __int_as_float(p3.y);
#pragma unroll
        for (int j = 0; j < 8; ++j) {
            acc[j] += v0 * bf2f(a0[j]);
            acc[j] += v1 * bf2f(a1[j]);
            acc[j] += v2 * bf2f(a2[j]);
            acc[j] += v3 * bf2f(a3[j]);
        }
    }
    for (; i < s1; ++i) {
        const int2 p = packed[i];
        const float v = __int_as_float(p.y);
        const ush8 a = *reinterpret_cast<const ush8*>(support + (size_t)p.x * kOutF + f8);
#pragma unroll
        for (int j = 0; j < 8; ++j) acc[j] += v * bf2f(a[j]);
    }

    float4 o0 = make_float4(fmaxf(acc[0], 0.f), fmaxf(acc[1], 0.f),
                            fmaxf(acc[2], 0.f), fmaxf(acc[3], 0.f));
    float4 o1 = make_float4(fmaxf(acc[4], 0.f), fmaxf(acc[5], 0.f),
                            fmaxf(acc[6], 0.f), fmaxf(acc[7], 0.f));
    *reinterpret_cast<float4*>(out + (size_t)n * kOutF + f8)     = o0;
    *reinterpret_cast<float4*>(out + (size_t)n * kOutF + f8 + 4) = o1;
}

extern "C" void kernel_launch(void* const* d_in, const int* in_sizes, int n_in,
                              void* d_out, int out_size, void* d_ws, size_t ws_size,
                              hipStream_t stream) {
    const float* x    = (const float*)d_in[0];
    const int*   erow = (const int*)  d_in[1];
    const int*   ecol = (const int*)  d_in[2];
    const float* eval = (const float*)d_in[3];
    const float* W    = (const float*)d_in[4];
    const float* b    = (const float*)d_in[5];
    float* out = (float*)d_out;

    char* ws = (char*)d_ws;
    unsigned short* support = (unsigned short*)(ws);       // 25,600,000 B
    int2* packed    = (int2*)(ws + 25600000);              // 12,800,000 B
    int*  counts    = (int*) (ws + 38400000);              //    400,000 B
    int*  row_start = (int*) (ws + 38800000);              //    400,004 B
    int*  cursor    = (int*) (ws + 39200008);              //    400,000 B
    int*  blockSums = (int*) (ws + 39600008);              //      1,564 B
    int*  blockOffs = (int*) (ws + 39601576);              //      1,564 B
    // counts is dead after scan1 -> reuse its storage for the 256 bucket cursors
    int*  bucket_cursor = counts;

    // 1) support = bf16(x@W + b)
    gcn_gemm<<<kGemmBlocks, 256, 0, stream>>>(x, W, b, support);

    // 2) CSR build: hist -> scan -> coarse-bin -> per-bucket place
    hipMemsetAsync(counts, 0, (size_t)kNodes * sizeof(int), stream);
    gcn_hist  <<<1024, 256, 0, stream>>>(erow, counts);
    gcn_scan1 <<<kScanBlocks, 256, 0, stream>>>(counts, row_start, blockSums);
    gcn_scan2 <<<1, 512, 0, stream>>>(blockSums, blockOffs);
    gcn_scan3 <<<kScanBlocks, 256, 0, stream>>>(row_start, blockOffs, cursor, bucket_cursor);
    gcn_bin   <<<kBucketBlocks, 256, 0, stream>>>(erow, ecol, eval, bucket_cursor, packed);
    gcn_place <<<kNB, 256, 0, stream>>>(row_start, cursor, packed);

    // 3) aggregate + relu
    gcn_aggregate<<<(kNodes + 15) / 16, 256, 0, stream>>>(row_start, packed, support, out);
}

// Round 2
// 419.855 us; speedup vs baseline: 1.0357x; 1.0089x over previous
//
#include <hip/hip_runtime.h>

// GCN layer: out = relu(segment_sum(edge_val * (x@W + b)[edge_col] -> edge_row))
// N=100000 nodes, E=1600000 edges, 256 -> 128 features, fp32 in/out.
//
// Round 8: gcn_gemm was latency-serialized. rocprof r7: dur 85us with
// MfmaUtil 2.8 / VALUBusy 13.6 / HBM 11% -> all pipes idle; VGPR_Count=64
// shows the compiler's occupancy heuristic blocked load hoisting, so each
// of the 8 kc-steps per tile exposed a full ~900cy HBM round trip.
// Fix: (a) __launch_bounds__(256,2) frees the register budget; (b) the tile
// loop now issues all 16 float4 x-loads into registers up front (one latency
// window per tile instead of 8); (c) bf16 conversion in the hot path uses
// v_cvt_pk_bf16_f32 (1 inst / 2 elems, RNE) instead of 4-op bitmath.
// CSR build (hist/scan/bin/place) and aggregate unchanged from r7.

constexpr int kNodes = 100000;
constexpr int kEdges = 1600000;
constexpr int kInF   = 256;
constexpr int kOutF  = 128;
constexpr int kScanBlocks = (kNodes + 255) / 256;   // 391
constexpr int kBucketBlocks = 800;                  // 800*256*8 >= E
constexpr int kGemmBlocks = 1250;                   // 6250 tiles / 5 per block

constexpr int kNB = 256;                            // coarse buckets
constexpr int kRB = 391;                            // rows per bucket (256*391 >= N)
constexpr int kCap = 7808;                          // LDS-staged edges per bucket (62.5KB)

typedef __attribute__((ext_vector_type(8))) short short8;
typedef __attribute__((ext_vector_type(8))) unsigned short ush8;
typedef __attribute__((ext_vector_type(4))) float floatx4;

__device__ inline unsigned short f2bf_rne(float f) {
    unsigned int u = __float_as_uint(f);
    unsigned int r = u + 0x7FFFu + ((u >> 16) & 1u);
    return (unsigned short)(r >> 16);
}
__device__ inline float bf2f(unsigned short h) {
    return __uint_as_float(((unsigned int)h) << 16);
}

// 8 fp32 -> 8 bf16 (RNE) via 4x v_cvt_pk_bf16_f32.
// dst bits: u[k][15:0]=bf16(src0), u[k][31:16]=bf16(src1) -> elem order matches short8.
__device__ inline short8 cvt8_bf16(const float4 a, const float4 b) {
    union { short8 s; unsigned int u[4]; } r;
    asm("v_cvt_pk_bf16_f32 %0, %1, %2" : "=v"(r.u[0]) : "v"(a.x), "v"(a.y));
    asm("v_cvt_pk_bf16_f32 %0, %1, %2" : "=v"(r.u[1]) : "v"(a.z), "v"(a.w));
    asm("v_cvt_pk_bf16_f32 %0, %1, %2" : "=v"(r.u[2]) : "v"(b.x), "v"(b.y));
    asm("v_cvt_pk_bf16_f32 %0, %1, %2" : "=v"(r.u[3]) : "v"(b.z), "v"(b.w));
    return r.s;
}

// ---------------------------------------------------------------------------
// GEMM: support_bf[N][128] = bf16(x[N][256] @ W[256][128] + b)
// Block = 4 waves; wave wv owns cols wv*32..wv*32+31, B-frags in 64 VGPRs.
// Per tile: hoist ALL 16 float4 x-loads (one HBM latency window), then
// convert (cvt_pk) + MFMA. __launch_bounds__(256,2) gives the regs for it.
// ---------------------------------------------------------------------------
__global__ __launch_bounds__(256, 2) void gcn_gemm(const float* __restrict__ x,
                                                   const float* __restrict__ W,
                                                   const float* __restrict__ b,
                                                   unsigned short* __restrict__ support) {
    const int lane = threadIdx.x & 63;
    const int wv   = threadIdx.x >> 6;
    const int rowl = lane & 15;
    const int quad = lane >> 4;
    const int colbase = wv * 32;

    // ---- one-time: B fragments for this wave's 32 cols (64 VGPRs) ----
    short8 bfrag[2][8];
#pragma unroll
    for (int ct = 0; ct < 2; ++ct) {
        const int col = colbase + ct * 16 + rowl;
#pragma unroll
        for (int kc = 0; kc < 8; ++kc) {
            const int kb = kc * 32 + quad * 8;
            short8 f;
#pragma unroll
            for (int j = 0; j < 8; ++j)
                f[j] = (short)f2bf_rne(W[(size_t)(kb + j) * kOutF + col]);
            bfrag[ct][kc] = f;
        }
    }
    const float bias0 = b[colbase + rowl];
    const float bias1 = b[colbase + 16 + rowl];

    // ---- block-strided 16-row tiles; all 4 waves share each tile ----
    for (int tile = blockIdx.x; tile < kNodes / 16; tile += gridDim.x) {
        const int r0 = tile * 16;
        const float* xrow = x + (size_t)(r0 + rowl) * kInF + quad * 8;

        // issue all 16 loads first: one latency window per tile, not eight
        float4 v[16];
#pragma unroll
        for (int kc = 0; kc < 8; ++kc) {
            v[2 * kc]     = *reinterpret_cast<const float4*>(xrow + kc * 32);
            v[2 * kc + 1] = *reinterpret_cast<const float4*>(xrow + kc * 32 + 4);
        }

        floatx4 acc0 = {0.f, 0.f, 0.f, 0.f};
        floatx4 acc1 = {0.f, 0.f, 0.f, 0.f};
#pragma unroll
        for (int kc = 0; kc < 8; ++kc) {
            const short8 a = cvt8_bf16(v[2 * kc], v[2 * kc + 1]);
            acc0 = __builtin_amdgcn_mfma_f32_16x16x32_bf16(a, bfrag[0][kc], acc0, 0, 0, 0);
            acc1 = __builtin_amdgcn_mfma_f32_16x16x32_bf16(a, bfrag[1][kc], acc1, 0, 0, 0);
        }
        // epilogue: rows r0+quad*4+reg, cols colbase+{rowl, 16+rowl}
#pragma unroll
        for (int reg = 0; reg < 4; ++reg) {
            const size_t rbase = (size_t)(r0 + quad * 4 + reg) * kOutF + colbase;
            support[rbase + rowl]      = f2bf_rne(acc0[reg] + bias0);
            support[rbase + 16 + rowl] = f2bf_rne(acc1[reg] + bias1);
        }
    }
}

// ---------------------------------------------------------------------------
// CSR step 1: per-row edge counts (fire-and-forget atomics).
// ---------------------------------------------------------------------------
__global__ __launch_bounds__(256) void gcn_hist(const int* __restrict__ erow,
                                                int* __restrict__ counts) {
    const int stride = gridDim.x * blockDim.x;
    for (int e = blockIdx.x * blockDim.x + threadIdx.x; e < kEdges; e += stride)
        atomicAdd(&counts[erow[e]], 1);
}

// ---------------------------------------------------------------------------
// CSR step 2: two-level exclusive scan.
// ---------------------------------------------------------------------------
__global__ __launch_bounds__(256) void gcn_scan1(const int* __restrict__ counts,
                                                 int* __restrict__ row_start,
                                                 int* __restrict__ blockSums) {
    __shared__ int s[256];
    const int i = blockIdx.x * 256 + threadIdx.x;
    const int v = (i < kNodes) ? counts[i] : 0;
    s[threadIdx.x] = v;
    __syncthreads();
#pragma unroll
    for (int off = 1; off < 256; off <<= 1) {
        const int t = (threadIdx.x >= off) ? s[threadIdx.x - off] : 0;
        __syncthreads();
        s[threadIdx.x] += t;
        __syncthreads();
    }
    if (i < kNodes) row_start[i] = s[threadIdx.x] - v;
    if (threadIdx.x == 255) blockSums[blockIdx.x] = s[255];
}

__global__ __launch_bounds__(512) void gcn_scan2(const int* __restrict__ blockSums,
                                                 int* __restrict__ blockOffs) {
    __shared__ int s[512];
    const int v = (threadIdx.x < kScanBlocks) ? blockSums[threadIdx.x] : 0;
    s[threadIdx.x] = v;
    __syncthreads();
#pragma unroll
    for (int off = 1; off < 512; off <<= 1) {
        const int t = (threadIdx.x >= off) ? s[threadIdx.x - off] : 0;
        __syncthreads();
        s[threadIdx.x] += t;
        __syncthreads();
    }
    if (threadIdx.x < kScanBlocks) blockOffs[threadIdx.x] = s[threadIdx.x] - v;
}

__global__ __launch_bounds__(256) void gcn_scan3(int* __restrict__ row_start,
                                                 const int* __restrict__ blockOffs,
                                                 int* __restrict__ cursor,
                                                 int* __restrict__ bucket_cursor) {
    const int i = blockIdx.x * 256 + threadIdx.x;
    if (i < kNodes) {
        const int rs = row_start[i] + blockOffs[blockIdx.x];
        row_start[i] = rs;
        cursor[i]    = rs;
        if (i % kRB == 0) bucket_cursor[i / kRB] = rs;   // bucket base = row_start[bk*391]
    }
    if (i == 0) row_start[kNodes] = kEdges;
}

// ---------------------------------------------------------------------------
// Phase A: bin edges into 256 coarse buckets (391 rows each), write-combined.
// packed.x = (row_local<<17) | col. packed.y = val.
// ---------------------------------------------------------------------------
__global__ __launch_bounds__(256) void gcn_bin(const int* __restrict__ erow,
                                               const int* __restrict__ ecol,
                                               const float* __restrict__ eval,
                                               int* __restrict__ bucket_cursor,
                                               int2* __restrict__ packed) {
    __shared__ int cnt[kNB];
    __shared__ int base[kNB];
    __shared__ int rk[kNB];
    const int T   = kBucketBlocks * 256;
    const int tid = blockIdx.x * 256 + threadIdx.x;

    cnt[threadIdx.x] = 0;
    rk[threadIdx.x]  = 0;

    int bk[8], pk[8], vb[8];
    bool ok[8];
#pragma unroll
    for (int i = 0; i < 8; ++i) {
        const int e = tid + i * T;
        ok[i] = (e < kEdges);
        const int r = ok[i] ? erow[e] : 0;
        const int c = ok[i] ? ecol[e] : 0;
        const float v = ok[i] ? eval[e] : 0.f;
        const unsigned int b = (unsigned int)r / (unsigned int)kRB;  // compiler magic-div
        bk[i] = (int)b;
        pk[i] = ((r - (int)b * kRB) << 17) | c;
        vb[i] = __float_as_int(v);
    }
    __syncthreads();
#pragma unroll
    for (int i = 0; i < 8; ++i)
        if (ok[i]) atomicAdd(&cnt[bk[i]], 1);
    __syncthreads();
    const int c = cnt[threadIdx.x];
    base[threadIdx.x] = c ? atomicAdd(&bucket_cursor[threadIdx.x], c) : 0;
    __syncthreads();
#pragma unroll
    for (int i = 0; i < 8; ++i) {
        if (ok[i]) {
            const int r = atomicAdd(&rk[bk[i]], 1);
            packed[base[bk[i]] + r] = make_int2(pk[i], vb[i]);
        }
    }
}

// ---------------------------------------------------------------------------
// Phase B: per-bucket in-place placement (LDS staging, read-before-write).
// ---------------------------------------------------------------------------
__global__ __launch_bounds__(256) void gcn_place(const int* __restrict__ row_start,
                                                 int* __restrict__ cursor,
                                                 int2* __restrict__ packed) {
    __shared__ int2 st[kCap];
    const int bk = blockIdx.x;
    const int r0 = bk * kRB;
    const int r1 = min(r0 + kRB, kNodes);
    if (r0 >= kNodes) return;
    const int s0 = row_start[r0];
    const int s1 = row_start[r1];
    const int size   = s1 - s0;
    const int staged = min(size, kCap);

    for (int i = threadIdx.x; i < staged; i += 256)
        st[i] = packed[s0 + i];

    int2 tail[8];
    int  nt = 0;
    for (int i = kCap + threadIdx.x; i < size; i += 256)
        if (nt < 8) tail[nt++] = packed[s0 + i];

    __syncthreads();   // every edge of the bucket read before any write

    for (int i = threadIdx.x; i < staged; i += 256) {
        const int2 p  = st[i];
        const int row = r0 + (p.x >> 17);
        const int pos = atomicAdd(&cursor[row], 1);
        packed[pos] = make_int2(p.x & 0x1FFFF, p.y);
    }
#pragma unroll
    for (int t = 0; t < 8; ++t) {
        if (t < nt) {
            const int2 p  = tail[t];
            const int row = r0 + (p.x >> 17);
            const int pos = atomicAdd(&cursor[row], 1);
            packed[pos] = make_int2(p.x & 0x1FFFF, p.y);
        }
    }
}

// ---------------------------------------------------------------------------
// Aggregate + ReLU (unchanged): 16 lanes/node, bf16x8 gathers, fp32 acc.
// ---------------------------------------------------------------------------
__global__ __launch_bounds__(256) void gcn_aggregate(const int* __restrict__ row_start,
                                                     const int2* __restrict__ packed,
                                                     const unsigned short* __restrict__ support,
                                                     float* __restrict__ out) {
    const int n  = blockIdx.x * 16 + (threadIdx.x >> 4);
    const int f8 = (threadIdx.x & 15) * 8;
    if (n >= kNodes) return;
    const int s0 = row_start[n];
    const int s1 = row_start[n + 1];
    float acc[8];
#pragma unroll
    for (int j = 0; j < 8; ++j) acc[j] = 0.f;

    int i = s0;
    for (; i + 3 < s1; i += 4) {
        const int2 p0 = packed[i];
        const int2 p1 = packed[i + 1];
        const int2 p2 = packed[i + 2];
        const int2 p3 = packed[i + 3];
        const ush8 a0 = *reinterpret_cast<const ush8*>(support + (size_t)p0.x * kOutF + f8);
        const ush8 a1 = *reinterpret_cast<const ush8*>(support + (size_t)p1.x * kOutF + f8);
        const ush8 a2 = *reinterpret_cast<const ush8*>(support + (size_t)p2.x * kOutF + f8);
        const ush8 a3 = *reinterpret_cast<const ush8*>(support + (size_t)p3.x * kOutF + f8);
        const float v0 = __int_as_float(p0.y), v1 = __int_as_float(p1.y);
        const float v2 = __int_as_float(p2.y), v3 = __int_as_float(p3.y);
#pragma unroll
        for (int j = 0; j < 8; ++j) {
            acc[j] += v0 * bf2f(a0[j]);
            acc[j] += v1 * bf2f(a1[j]);
            acc[j] += v2 * bf2f(a2[j]);
            acc[j] += v3 * bf2f(a3[j]);
        }
    }
    for (; i < s1; ++i) {
        const int2 p = packed[i];
        const float v = __int_as_float(p.y);
        const ush8 a = *reinterpret_cast<const ush8*>(support + (size_t)p.x * kOutF + f8);
#pragma unroll
        for (int j = 0; j < 8; ++j) acc[j] += v * bf2f(a[j]);
    }

    float4 o0 = make_float4(fmaxf(acc[0], 0.f), fmaxf(acc[1], 0.f),
                            fmaxf(acc[2], 0.f), fmaxf(acc[3], 0.f));
    float4 o1 = make_float4(fmaxf(acc[4], 0.f), fmaxf(acc[5], 0.f),
                            fmaxf(acc[6], 0.f), fmaxf(acc[7], 0.f));
    *reinterpret_cast<float4*>(out + (size_t)n * kOutF + f8)     = o0;
    *reinterpret_cast<float4*>(out + (size_t)n * kOutF + f8 + 4) = o1;
}

extern "C" void kernel_launch(void* const* d_in, const int* in_sizes, int n_in,
                              void* d_out, int out_size, void* d_ws, size_t ws_size,
                              hipStream_t stream) {
    const float* x    = (const float*)d_in[0];
    const int*   erow = (const int*)  d_in[1];
    const int*   ecol = (const int*)  d_in[2];
    const float* eval = (const float*)d_in[3];
    const float* W    = (const float*)d_in[4];
    const float* b    = (const float*)d_in[5];
    float* out = (float*)d_out;

    char* ws = (char*)d_ws;
    unsigned short* support = (unsigned short*)(ws);       // 25,600,000 B
    int2* packed    = (int2*)(ws + 25600000);              // 12,800,000 B
    int*  counts    = (int*) (ws + 38400000);              //    400,000 B
    int*  row_start = (int*) (ws + 38800000);              //    400,004 B
    int*  cursor    = (int*) (ws + 39200008);              //    400,000 B
    int*  blockSums = (int*) (ws + 39600008);              //      1,564 B
    int*  blockOffs = (int*) (ws + 39601576);              //      1,564 B
    // counts is dead after scan1 -> reuse its storage for the 256 bucket cursors
    int*  bucket_cursor = counts;

    // 1) support = bf16(x@W + b)
    gcn_gemm<<<kGemmBlocks, 256, 0, stream>>>(x, W, b, support);

    // 2) CSR build: hist -> scan -> coarse-bin -> per-bucket place
    hipMemsetAsync(counts, 0, (size_t)kNodes * sizeof(int), stream);
    gcn_hist  <<<1024, 256, 0, stream>>>(erow, counts);
    gcn_scan1 <<<kScanBlocks, 256, 0, stream>>>(counts, row_start, blockSums);
    gcn_scan2 <<<1, 512, 0, stream>>>(blockSums, blockOffs);
    gcn_scan3 <<<kScanBlocks, 256, 0, stream>>>(row_start, blockOffs, cursor, bucket_cursor);
    gcn_bin   <<<kBucketBlocks, 256, 0, stream>>>(erow, ecol, eval, bucket_cursor, packed);
    gcn_place <<<kNB, 256, 0, stream>>>(row_start, cursor, packed);

    // 3) aggregate + relu
    gcn_aggregate<<<(kNodes + 15) / 16, 256, 0, stream>>>(row_start, packed, support, out);
}

// Round 3
// 398.680 us; speedup vs baseline: 1.0908x; 1.0531x over previous
//
#include <hip/hip_runtime.h>

// GCN layer: out = relu(segment_sum(edge_val * (x@W + b)[edge_col] -> edge_row))
// N=100000 nodes, E=1600000 edges, 256 -> 128 features, fp32 in/out.
//
// Round 9: gcn_gemm stays ~95us across r7/r8 because its x-loads are
// 16-line gathers (lane i -> row i&15, 1KB stride) issued 4x redundantly
// (all 4 waves load the same tile), and the compiler refuses to hoist a
// register pipeline (r8: VGPR_Count=52 despite launch_bounds(256,2) -> the
// 16 float4 loads were re-sunk, one latency window per kc). Fix per the
// guide's m93->m97 ladder step: the 16-row tile is a CONTIGUOUS 16KB block
// of x, so stage it ONCE per block with async global_load_lds (dense 16B
// per lane, no VGPR round-trip), double-buffered so tile t+1's stage hides
// under tile t's MFMA. ds_read_b128 fragments from LDS with a both-sides
// XOR swizzle (granule ^= row&7; pre-swizzled global source + swizzled
// read, linear LDS dest) to break the 1KB-row-stride bank conflict.
// CSR build (hist/scan/bin/place) and aggregate unchanged from r7/r8.

constexpr int kNodes = 100000;
constexpr int kEdges = 1600000;
constexpr int kInF   = 256;
constexpr int kOutF  = 128;
constexpr int kTiles = kNodes / 16;                 // 6250
constexpr int kScanBlocks = (kNodes + 255) / 256;   // 391
constexpr int kBucketBlocks = 800;                  // 800*256*8 >= E
constexpr int kGemmBlocks = 1250;                   // 5 tiles per block

constexpr int kNB = 256;                            // coarse buckets
constexpr int kRB = 391;                            // rows per bucket (256*391 >= N)
constexpr int kCap = 7808;                          // LDS-staged edges per bucket (62.5KB)

typedef __attribute__((ext_vector_type(8))) short short8;
typedef __attribute__((ext_vector_type(8))) unsigned short ush8;
typedef __attribute__((ext_vector_type(4))) float floatx4;

__device__ inline unsigned short f2bf_rne(float f) {
    unsigned int u = __float_as_uint(f);
    unsigned int r = u + 0x7FFFu + ((u >> 16) & 1u);
    return (unsigned short)(r >> 16);
}
__device__ inline float bf2f(unsigned short h) {
    return __uint_as_float(((unsigned int)h) << 16);
}

// 8 fp32 -> 8 bf16 (RNE) via 4x v_cvt_pk_bf16_f32.
__device__ inline short8 cvt8_bf16(const float4 a, const float4 b) {
    union { short8 s; unsigned int u[4]; } r;
    asm("v_cvt_pk_bf16_f32 %0, %1, %2" : "=v"(r.u[0]) : "v"(a.x), "v"(a.y));
    asm("v_cvt_pk_bf16_f32 %0, %1, %2" : "=v"(r.u[1]) : "v"(a.z), "v"(a.w));
    asm("v_cvt_pk_bf16_f32 %0, %1, %2" : "=v"(r.u[2]) : "v"(b.x), "v"(b.y));
    asm("v_cvt_pk_bf16_f32 %0, %1, %2" : "=v"(r.u[3]) : "v"(b.z), "v"(b.w));
    return r.s;
}

// async 16B global->LDS (dest = wave-uniform base + lane*16)
__device__ inline void gload_lds16(const void* g, void* l) {
    __builtin_amdgcn_global_load_lds(
        (const __attribute__((address_space(1))) unsigned int*)g,
        (__attribute__((address_space(3))) unsigned int*)l,
        16, 0, 0);
}

// ---------------------------------------------------------------------------
// GEMM: support_bf[N][128] = bf16(x[N][256] @ W[256][128] + b)
// Block = 4 waves; wave wv owns cols wv*32..wv*32+31, B-frags in regs.
// A-tile (16 rows x 256 f32 = 16KB, contiguous in x) staged via
// global_load_lds, double-buffered. XOR swizzle granule^=(row&7) applied on
// BOTH the global source and the LDS read (linear LDS dest, rule #21).
// ---------------------------------------------------------------------------
__global__ __launch_bounds__(256) void gcn_gemm(const float* __restrict__ x,
                                                const float* __restrict__ W,
                                                const float* __restrict__ b,
                                                unsigned short* __restrict__ support) {
    __shared__ __align__(16) float lbuf[2][4096];   // 2 x 16KB

    const int lane = threadIdx.x & 63;
    const int wv   = threadIdx.x >> 6;
    const int rowl = lane & 15;
    const int quad = lane >> 4;
    const int colbase = wv * 32;

    // ---- one-time: B fragments for this wave's 32 cols ----
    short8 bfrag[2][8];
#pragma unroll
    for (int ct = 0; ct < 2; ++ct) {
        const int col = colbase + ct * 16 + rowl;
#pragma unroll
        for (int kc = 0; kc < 8; ++kc) {
            const int kb = kc * 32 + quad * 8;
            short8 f;
#pragma unroll
            for (int j = 0; j < 8; ++j)
                f[j] = (short)f2bf_rne(W[(size_t)(kb + j) * kOutF + col]);
            bfrag[ct][kc] = f;
        }
    }
    const float bias0 = b[colbase + rowl];
    const float bias1 = b[colbase + 16 + rowl];

    const int G = gridDim.x;
    int t = blockIdx.x;

    // stage(tile, buf): 4 rows per wave (row = i*4 + wv), 64 granules/row,
    // lane stages LDS granule (row, lane) sourcing global granule
    // (row, lane ^ (row&7)) -- dense within the row, permuted order.
#define GEMM_STAGE(buf_, tile_)                                                   \
    do {                                                                          \
        const float* tb_ = x + (size_t)(tile_) * 16 * kInF;                       \
        _Pragma("unroll")                                                         \
        for (int i_ = 0; i_ < 4; ++i_) {                                          \
            const int row_ = i_ * 4 + wv;                                         \
            gload_lds16(tb_ + (size_t)row_ * kInF + ((lane ^ (row_ & 7)) << 2),   \
                        &lbuf[buf_][row_ << 8]);                                  \
        }                                                                         \
    } while (0)

    if (t < kTiles) GEMM_STAGE(0, t);
    int cur = 0;

    for (; t < kTiles; t += G) {
        const int tn = t + G;
        asm volatile("s_waitcnt vmcnt(0)" ::: "memory");
        __syncthreads();                        // buf[cur] staged & visible
        if (tn < kTiles) GEMM_STAGE(cur ^ 1, tn);

        const int r0 = t * 16;
        const float* base = &lbuf[cur][rowl << 8];
        const int rsw = rowl & 7;
        floatx4 acc0 = {0.f, 0.f, 0.f, 0.f};
        floatx4 acc1 = {0.f, 0.f, 0.f, 0.f};
#pragma unroll
        for (int kc = 0; kc < 8; ++kc) {
            const int g0 = (kc << 3) + (quad << 1);
            const float4 v0 = *reinterpret_cast<const float4*>(base + ((g0 ^ rsw) << 2));
            const float4 v1 = *reinterpret_cast<const float4*>(base + (((g0 + 1) ^ rsw) << 2));
            const short8 a = cvt8_bf16(v0, v1);
            acc0 = __builtin_amdgcn_mfma_f32_16x16x32_bf16(a, bfrag[0][kc], acc0, 0, 0, 0);
            acc1 = __builtin_amdgcn_mfma_f32_16x16x32_bf16(a, bfrag[1][kc], acc1, 0, 0, 0);
        }
        // epilogue: rows r0+quad*4+reg, cols colbase+{rowl, 16+rowl}
#pragma unroll
        for (int reg = 0; reg < 4; ++reg) {
            const size_t rbase = (size_t)(r0 + quad * 4 + reg) * kOutF + colbase;
            support[rbase + rowl]      = f2bf_rne(acc0[reg] + bias0);
            support[rbase + 16 + rowl] = f2bf_rne(acc1[reg] + bias1);
        }
        cur ^= 1;
    }
#undef GEMM_STAGE
}

// ---------------------------------------------------------------------------
// CSR step 1: per-row edge counts (fire-and-forget atomics).
// ---------------------------------------------------------------------------
__global__ __launch_bounds__(256) void gcn_hist(const int* __restrict__ erow,
                                                int* __restrict__ counts) {
    const int stride = gridDim.x * blockDim.x;
    for (int e = blockIdx.x * blockDim.x + threadIdx.x; e < kEdges; e += stride)
        atomicAdd(&counts[erow[e]], 1);
}

// ---------------------------------------------------------------------------
// CSR step 2: two-level exclusive scan.
// ---------------------------------------------------------------------------
__global__ __launch_bounds__(256) void gcn_scan1(const int* __restrict__ counts,
                                                 int* __restrict__ row_start,
                                                 int* __restrict__ blockSums) {
    __shared__ int s[256];
    const int i = blockIdx.x * 256 + threadIdx.x;
    const int v = (i < kNodes) ? counts[i] : 0;
    s[threadIdx.x] = v;
    __syncthreads();
#pragma unroll
    for (int off = 1; off < 256; off <<= 1) {
        const int t = (threadIdx.x >= off) ? s[threadIdx.x - off] : 0;
        __syncthreads();
        s[threadIdx.x] += t;
        __syncthreads();
    }
    if (i < kNodes) row_start[i] = s[threadIdx.x] - v;
    if (threadIdx.x == 255) blockSums[blockIdx.x] = s[255];
}

__global__ __launch_bounds__(512) void gcn_scan2(const int* __restrict__ blockSums,
                                                 int* __restrict__ blockOffs) {
    __shared__ int s[512];
    const int v = (threadIdx.x < kScanBlocks) ? blockSums[threadIdx.x] : 0;
    s[threadIdx.x] = v;
    __syncthreads();
#pragma unroll
    for (int off = 1; off < 512; off <<= 1) {
        const int t = (threadIdx.x >= off) ? s[threadIdx.x - off] : 0;
        __syncthreads();
        s[threadIdx.x] += t;
        __syncthreads();
    }
    if (threadIdx.x < kScanBlocks) blockOffs[threadIdx.x] = s[threadIdx.x] - v;
}

__global__ __launch_bounds__(256) void gcn_scan3(int* __restrict__ row_start,
                                                 const int* __restrict__ blockOffs,
                                                 int* __restrict__ cursor,
                                                 int* __restrict__ bucket_cursor) {
    const int i = blockIdx.x * 256 + threadIdx.x;
    if (i < kNodes) {
        const int rs = row_start[i] + blockOffs[blockIdx.x];
        row_start[i] = rs;
        cursor[i]    = rs;
        if (i % kRB == 0) bucket_cursor[i / kRB] = rs;   // bucket base = row_start[bk*391]
    }
    if (i == 0) row_start[kNodes] = kEdges;
}

// ---------------------------------------------------------------------------
// Phase A: bin edges into 256 coarse buckets (391 rows each), write-combined.
// packed.x = (row_local<<17) | col. packed.y = val.
// ---------------------------------------------------------------------------
__global__ __launch_bounds__(256) void gcn_bin(const int* __restrict__ erow,
                                               const int* __restrict__ ecol,
                                               const float* __restrict__ eval,
                                               int* __restrict__ bucket_cursor,
                                               int2* __restrict__ packed) {
    __shared__ int cnt[kNB];
    __shared__ int base[kNB];
    __shared__ int rk[kNB];
    const int T   = kBucketBlocks * 256;
    const int tid = blockIdx.x * 256 + threadIdx.x;

    cnt[threadIdx.x] = 0;
    rk[threadIdx.x]  = 0;

    int bk[8], pk[8], vb[8];
    bool ok[8];
#pragma unroll
    for (int i = 0; i < 8; ++i) {
        const int e = tid + i * T;
        ok[i] = (e < kEdges);
        const int r = ok[i] ? erow[e] : 0;
        const int c = ok[i] ? ecol[e] : 0;
        const float v = ok[i] ? eval[e] : 0.f;
        const unsigned int b = (unsigned int)r / (unsigned int)kRB;  // compiler magic-div
        bk[i] = (int)b;
        pk[i] = ((r - (int)b * kRB) << 17) | c;
        vb[i] = __float_as_int(v);
    }
    __syncthreads();
#pragma unroll
    for (int i = 0; i < 8; ++i)
        if (ok[i]) atomicAdd(&cnt[bk[i]], 1);
    __syncthreads();
    const int c = cnt[threadIdx.x];
    base[threadIdx.x] = c ? atomicAdd(&bucket_cursor[threadIdx.x], c) : 0;
    __syncthreads();
#pragma unroll
    for (int i = 0; i < 8; ++i) {
        if (ok[i]) {
            const int r = atomicAdd(&rk[bk[i]], 1);
            packed[base[bk[i]] + r] = make_int2(pk[i], vb[i]);
        }
    }
}

// ---------------------------------------------------------------------------
// Phase B: per-bucket in-place placement (LDS staging, read-before-write).
// ---------------------------------------------------------------------------
__global__ __launch_bounds__(256) void gcn_place(const int* __restrict__ row_start,
                                                 int* __restrict__ cursor,
                                                 int2* __restrict__ packed) {
    __shared__ int2 st[kCap];
    const int bk = blockIdx.x;
    const int r0 = bk * kRB;
    const int r1 = min(r0 + kRB, kNodes);
    if (r0 >= kNodes) return;
    const int s0 = row_start[r0];
    const int s1 = row_start[r1];
    const int size   = s1 - s0;
    const int staged = min(size, kCap);

    for (int i = threadIdx.x; i < staged; i += 256)
        st[i] = packed[s0 + i];

    int2 tail[8];
    int  nt = 0;
    for (int i = kCap + threadIdx.x; i < size; i += 256)
        if (nt < 8) tail[nt++] = packed[s0 + i];

    __syncthreads();   // every edge of the bucket read before any write

    for (int i = threadIdx.x; i < staged; i += 256) {
        const int2 p  = st[i];
        const int row = r0 + (p.x >> 17);
        const int pos = atomicAdd(&cursor[row], 1);
        packed[pos] = make_int2(p.x & 0x1FFFF, p.y);
    }
#pragma unroll
    for (int t = 0; t < 8; ++t) {
        if (t < nt) {
            const int2 p  = tail[t];
            const int row = r0 + (p.x >> 17);
            const int pos = atomicAdd(&cursor[row], 1);
            packed[pos] = make_int2(p.x & 0x1FFFF, p.y);
        }
    }
}

// ---------------------------------------------------------------------------
// Aggregate + ReLU (unchanged): 16 lanes/node, bf16x8 gathers, fp32 acc.
// ---------------------------------------------------------------------------
__global__ __launch_bounds__(256) void gcn_aggregate(const int* __restrict__ row_start,
                                                     const int2* __restrict__ packed,
                                                     const unsigned short* __restrict__ support,
                                                     float* __restrict__ out) {
    const int n  = blockIdx.x * 16 + (threadIdx.x >> 4);
    const int f8 = (threadIdx.x & 15) * 8;
    if (n >= kNodes) return;
    const int s0 = row_start[n];
    const int s1 = row_start[n + 1];
    float acc[8];
#pragma unroll
    for (int j = 0; j < 8; ++j) acc[j] = 0.f;

    int i = s0;
    for (; i + 3 < s1; i += 4) {
        const int2 p0 = packed[i];
        const int2 p1 = packed[i + 1];
        const int2 p2 = packed[i + 2];
        const int2 p3 = packed[i + 3];
        const ush8 a0 = *reinterpret_cast<const ush8*>(support + (size_t)p0.x * kOutF + f8);
        const ush8 a1 = *reinterpret_cast<const ush8*>(support + (size_t)p1.x * kOutF + f8);
        const ush8 a2 = *reinterpret_cast<const ush8*>(support + (size_t)p2.x * kOutF + f8);
        const ush8 a3 = *reinterpret_cast<const ush8*>(support + (size_t)p3.x * kOutF + f8);
        const float v0 = __int_as_float(p0.y), v1 = __int_as_float(p1.y);
        const float v2 = __int_as_float(p2.y), v3 = __int_as_float(p3.y);
#pragma unroll
        for (int j = 0; j < 8; ++j) {
            acc[j] += v0 * bf2f(a0[j]);
            acc[j] += v1 * bf2f(a1[j]);
            acc[j] += v2 * bf2f(a2[j]);
            acc[j] += v3 * bf2f(a3[j]);
        }
    }
    for (; i < s1; ++i) {
        const int2 p = packed[i];
        const float v = __int_as_float(p.y);
        const ush8 a = *reinterpret_cast<const ush8*>(support + (size_t)p.x * kOutF + f8);
#pragma unroll
        for (int j = 0; j < 8; ++j) acc[j] += v * bf2f(a[j]);
    }

    float4 o0 = make_float4(fmaxf(acc[0], 0.f), fmaxf(acc[1], 0.f),
                            fmaxf(acc[2], 0.f), fmaxf(acc[3], 0.f));
    float4 o1 = make_float4(fmaxf(acc[4], 0.f), fmaxf(acc[5], 0.f),
                            fmaxf(acc[6], 0.f), fmaxf(acc[7], 0.f));
    *reinterpret_cast<float4*>(out + (size_t)n * kOutF + f8)     = o0;
    *reinterpret_cast<float4*>(out + (size_t)n * kOutF + f8 + 4) = o1;
}

extern "C" void kernel_launch(void* const* d_in, const int* in_sizes, int n_in,
                              void* d_out, int out_size, void* d_ws, size_t ws_size,
                              hipStream_t stream) {
    const float* x    = (const float*)d_in[0];
    const int*   erow = (const int*)  d_in[1];
    const int*   ecol = (const int*)  d_in[2];
    const float* eval = (const float*)d_in[3];
    const float* W    = (const float*)d_in[4];
    const float* b    = (const float*)d_in[5];
    float* out = (float*)d_out;

    char* ws = (char*)d_ws;
    unsigned short* support = (unsigned short*)(ws);       // 25,600,000 B
    int2* packed    = (int2*)(ws + 25600000);              // 12,800,000 B
    int*  counts    = (int*) (ws + 38400000);              //    400,000 B
    int*  row_start = (int*) (ws + 38800000);              //    400,004 B
    int*  cursor    = (int*) (ws + 39200008);              //    400,000 B
    int*  blockSums = (int*) (ws + 39600008);              //      1,564 B
    int*  blockOffs = (int*) (ws + 39601576);              //      1,564 B
    // counts is dead after scan1 -> reuse its storage for the 256 bucket cursors
    int*  bucket_cursor = counts;

    // 1) support = bf16(x@W + b)
    gcn_gemm<<<kGemmBlocks, 256, 0, stream>>>(x, W, b, support);

    // 2) CSR build: hist -> scan -> coarse-bin -> per-bucket place
    hipMemsetAsync(counts, 0, (size_t)kNodes * sizeof(int), stream);
    gcn_hist  <<<1024, 256, 0, stream>>>(erow, counts);
    gcn_scan1 <<<kScanBlocks, 256, 0, stream>>>(counts, row_start, blockSums);
    gcn_scan2 <<<1, 512, 0, stream>>>(blockSums, blockOffs);
    gcn_scan3 <<<kScanBlocks, 256, 0, stream>>>(row_start, blockOffs, cursor, bucket_cursor);
    gcn_bin   <<<kBucketBlocks, 256, 0, stream>>>(erow, ecol, eval, bucket_cursor, packed);
    gcn_place <<<kNB, 256, 0, stream>>>(row_start, cursor, packed);

    // 3) aggregate + relu
    gcn_aggregate<<<(kNodes + 15) / 16, 256, 0, stream>>>(row_start, packed, support, out);
}

// Round 4
// 358.498 us; speedup vs baseline: 1.2130x; 1.1121x over previous
//
#include <hip/hip_runtime.h>

// GCN layer: out = relu(segment_sum(edge_val * (x@W + b)[edge_col] -> edge_row))
// N=100000 nodes, E=1600000 edges, 256 -> 128 features, fp32 in/out.
//
// Round 10: kill per-row device atomics. r9 rocprof: gcn_hist = 66us with
// VALUBusy 0.3 / FETCH 3MB / WRITE 49.9MB = 1.6M x 32B -> memory-side
// atomic RMW bound (~24G atomics/s); gcn_place's 1.6M global cursor
// atomics pay the same tax. Per-row counting moves into the per-bucket
// place kernel (LDS atomics + LDS scan over the bucket's <=391 rows);
// the global build only needs per-BUCKET totals:
//   gcn_bhist: LDS hist over 256 buckets -> 256 atomics/block (205K total)
//   gcn_bscan: single-block scan -> bucket_base[257] + bucket_cursor
//   gcn_bin:   unchanged (scatter into bucket regions, write-combined)
//   gcn_place: stage bucket in LDS -> LDS row hist -> LDS scan ->
//              write row_start -> scatter via LDS cursors (0 global atomics)
// gcn_hist/scan1/scan2/scan3 and the 400KB memset are deleted.
// gemm (r9: global_load_lds + dbuf + XOR swizzle) and aggregate unchanged.

constexpr int kNodes = 100000;
constexpr int kEdges = 1600000;
constexpr int kInF   = 256;
constexpr int kOutF  = 128;
constexpr int kTiles = kNodes / 16;                 // 6250
constexpr int kBucketBlocks = 800;                  // 800*256*8 >= E
constexpr int kGemmBlocks = 1250;                   // 5 tiles per block

constexpr int kNB = 256;                            // coarse buckets
constexpr int kRB = 391;                            // rows per bucket (256*391 >= N)
constexpr int kCap = 7424;                          // LDS-staged edges per bucket (58KB)

typedef __attribute__((ext_vector_type(8))) short short8;
typedef __attribute__((ext_vector_type(8))) unsigned short ush8;
typedef __attribute__((ext_vector_type(4))) float floatx4;

__device__ inline unsigned short f2bf_rne(float f) {
    unsigned int u = __float_as_uint(f);
    unsigned int r = u + 0x7FFFu + ((u >> 16) & 1u);
    return (unsigned short)(r >> 16);
}
__device__ inline float bf2f(unsigned short h) {
    return __uint_as_float(((unsigned int)h) << 16);
}

// 8 fp32 -> 8 bf16 (RNE) via 4x v_cvt_pk_bf16_f32.
__device__ inline short8 cvt8_bf16(const float4 a, const float4 b) {
    union { short8 s; unsigned int u[4]; } r;
    asm("v_cvt_pk_bf16_f32 %0, %1, %2" : "=v"(r.u[0]) : "v"(a.x), "v"(a.y));
    asm("v_cvt_pk_bf16_f32 %0, %1, %2" : "=v"(r.u[1]) : "v"(a.z), "v"(a.w));
    asm("v_cvt_pk_bf16_f32 %0, %1, %2" : "=v"(r.u[2]) : "v"(b.x), "v"(b.y));
    asm("v_cvt_pk_bf16_f32 %0, %1, %2" : "=v"(r.u[3]) : "v"(b.z), "v"(b.w));
    return r.s;
}

// async 16B global->LDS (dest = wave-uniform base + lane*16)
__device__ inline void gload_lds16(const void* g, void* l) {
    __builtin_amdgcn_global_load_lds(
        (const __attribute__((address_space(1))) unsigned int*)g,
        (__attribute__((address_space(3))) unsigned int*)l,
        16, 0, 0);
}

// ---------------------------------------------------------------------------
// GEMM: support_bf[N][128] = bf16(x[N][256] @ W[256][128] + b)   (r9, kept)
// ---------------------------------------------------------------------------
__global__ __launch_bounds__(256) void gcn_gemm(const float* __restrict__ x,
                                                const float* __restrict__ W,
                                                const float* __restrict__ b,
                                                unsigned short* __restrict__ support) {
    __shared__ __align__(16) float lbuf[2][4096];   // 2 x 16KB

    const int lane = threadIdx.x & 63;
    const int wv   = threadIdx.x >> 6;
    const int rowl = lane & 15;
    const int quad = lane >> 4;
    const int colbase = wv * 32;

    short8 bfrag[2][8];
#pragma unroll
    for (int ct = 0; ct < 2; ++ct) {
        const int col = colbase + ct * 16 + rowl;
#pragma unroll
        for (int kc = 0; kc < 8; ++kc) {
            const int kb = kc * 32 + quad * 8;
            short8 f;
#pragma unroll
            for (int j = 0; j < 8; ++j)
                f[j] = (short)f2bf_rne(W[(size_t)(kb + j) * kOutF + col]);
            bfrag[ct][kc] = f;
        }
    }
    const float bias0 = b[colbase + rowl];
    const float bias1 = b[colbase + 16 + rowl];

    const int G = gridDim.x;
    int t = blockIdx.x;

#define GEMM_STAGE(buf_, tile_)                                                   \
    do {                                                                          \
        const float* tb_ = x + (size_t)(tile_) * 16 * kInF;                       \
        _Pragma("unroll")                                                         \
        for (int i_ = 0; i_ < 4; ++i_) {                                          \
            const int row_ = i_ * 4 + wv;                                         \
            gload_lds16(tb_ + (size_t)row_ * kInF + ((lane ^ (row_ & 7)) << 2),   \
                        &lbuf[buf_][row_ << 8]);                                  \
        }                                                                         \
    } while (0)

    if (t < kTiles) GEMM_STAGE(0, t);
    int cur = 0;

    for (; t < kTiles; t += G) {
        const int tn = t + G;
        asm volatile("s_waitcnt vmcnt(0)" ::: "memory");
        __syncthreads();
        if (tn < kTiles) GEMM_STAGE(cur ^ 1, tn);

        const int r0 = t * 16;
        const float* base = &lbuf[cur][rowl << 8];
        const int rsw = rowl & 7;
        floatx4 acc0 = {0.f, 0.f, 0.f, 0.f};
        floatx4 acc1 = {0.f, 0.f, 0.f, 0.f};
#pragma unroll
        for (int kc = 0; kc < 8; ++kc) {
            const int g0 = (kc << 3) + (quad << 1);
            const float4 v0 = *reinterpret_cast<const float4*>(base + ((g0 ^ rsw) << 2));
            const float4 v1 = *reinterpret_cast<const float4*>(base + (((g0 + 1) ^ rsw) << 2));
            const short8 a = cvt8_bf16(v0, v1);
            acc0 = __builtin_amdgcn_mfma_f32_16x16x32_bf16(a, bfrag[0][kc], acc0, 0, 0, 0);
            acc1 = __builtin_amdgcn_mfma_f32_16x16x32_bf16(a, bfrag[1][kc], acc1, 0, 0, 0);
        }
#pragma unroll
        for (int reg = 0; reg < 4; ++reg) {
            const size_t rbase = (size_t)(r0 + quad * 4 + reg) * kOutF + colbase;
            support[rbase + rowl]      = f2bf_rne(acc0[reg] + bias0);
            support[rbase + 16 + rowl] = f2bf_rne(acc1[reg] + bias1);
        }
        cur ^= 1;
    }
#undef GEMM_STAGE
}

// ---------------------------------------------------------------------------
// Bucket histogram: per-block LDS hist over 256 buckets, one global atomic
// per (block,bucket). 205K atomics total vs 1.6M per-row.
// ---------------------------------------------------------------------------
__global__ __launch_bounds__(256) void gcn_bhist(const int* __restrict__ erow,
                                                 int* __restrict__ bucket_tot) {
    __shared__ int cnt[kNB];
    cnt[threadIdx.x] = 0;
    __syncthreads();
    const int stride = gridDim.x * blockDim.x;
    for (int e = blockIdx.x * blockDim.x + threadIdx.x; e < kEdges; e += stride)
        atomicAdd(&cnt[(unsigned int)erow[e] / (unsigned int)kRB], 1);
    __syncthreads();
    const int c = cnt[threadIdx.x];
    if (c) atomicAdd(&bucket_tot[threadIdx.x], c);
}

// ---------------------------------------------------------------------------
// Bucket scan: one block, exclusive scan of 256 totals -> bases + cursors.
// ---------------------------------------------------------------------------
__global__ __launch_bounds__(256) void gcn_bscan(const int* __restrict__ bucket_tot,
                                                 int* __restrict__ bucket_base,
                                                 int* __restrict__ bucket_cursor,
                                                 int* __restrict__ row_start) {
    __shared__ int s[256];
    const int v = bucket_tot[threadIdx.x];
    s[threadIdx.x] = v;
    __syncthreads();
#pragma unroll
    for (int off = 1; off < 256; off <<= 1) {
        const int t = (threadIdx.x >= off) ? s[threadIdx.x - off] : 0;
        __syncthreads();
        s[threadIdx.x] += t;
        __syncthreads();
    }
    const int excl = s[threadIdx.x] - v;
    bucket_base[threadIdx.x]   = excl;
    bucket_cursor[threadIdx.x] = excl;
    if (threadIdx.x == 255) {
        bucket_base[256]   = kEdges;
        row_start[kNodes]  = kEdges;
    }
}

// ---------------------------------------------------------------------------
// Phase A: bin edges into 256 coarse buckets, write-combined. (unchanged)
// packed.x = (row_local<<17) | col. packed.y = val.
// ---------------------------------------------------------------------------
__global__ __launch_bounds__(256) void gcn_bin(const int* __restrict__ erow,
                                               const int* __restrict__ ecol,
                                               const float* __restrict__ eval,
                                               int* __restrict__ bucket_cursor,
                                               int2* __restrict__ packed) {
    __shared__ int cnt[kNB];
    __shared__ int base[kNB];
    __shared__ int rk[kNB];
    const int T   = kBucketBlocks * 256;
    const int tid = blockIdx.x * 256 + threadIdx.x;

    cnt[threadIdx.x] = 0;
    rk[threadIdx.x]  = 0;

    int bk[8], pk[8], vb[8];
    bool ok[8];
#pragma unroll
    for (int i = 0; i < 8; ++i) {
        const int e = tid + i * T;
        ok[i] = (e < kEdges);
        const int r = ok[i] ? erow[e] : 0;
        const int c = ok[i] ? ecol[e] : 0;
        const float v = ok[i] ? eval[e] : 0.f;
        const unsigned int b = (unsigned int)r / (unsigned int)kRB;
        bk[i] = (int)b;
        pk[i] = ((r - (int)b * kRB) << 17) | c;
        vb[i] = __float_as_int(v);
    }
    __syncthreads();
#pragma unroll
    for (int i = 0; i < 8; ++i)
        if (ok[i]) atomicAdd(&cnt[bk[i]], 1);
    __syncthreads();
    const int c = cnt[threadIdx.x];
    base[threadIdx.x] = c ? atomicAdd(&bucket_cursor[threadIdx.x], c) : 0;
    __syncthreads();
#pragma unroll
    for (int i = 0; i < 8; ++i) {
        if (ok[i]) {
            const int r = atomicAdd(&rk[bk[i]], 1);
            packed[base[bk[i]] + r] = make_int2(pk[i], vb[i]);
        }
    }
}

// ---------------------------------------------------------------------------
// Phase B: per-bucket place, all bookkeeping in LDS. One block per bucket:
//   stage edges to LDS (+reg tail), LDS row-histogram (<=391 counters),
//   LDS Hillis-Steele scan (512-wide, 2 elems/thread), write row_start for
//   the bucket's rows, scatter via LDS cursors. Zero global atomics.
// In-place over packed is safe: all global reads precede the first barrier,
// all writes follow the scan barriers.
// ---------------------------------------------------------------------------
__global__ __launch_bounds__(256) void gcn_place(const int* __restrict__ bucket_base,
                                                 int* __restrict__ row_start,
                                                 int2* __restrict__ packed) {
    __shared__ int2 st[kCap];       // 59,392 B
    __shared__ int  s[512];         //  2,048 B  (row counts -> inclusive scan)
    __shared__ int  rcur[kRB + 1];  //  1,568 B  (row cursors)
    const int bk = blockIdx.x;
    const int r0 = bk * kRB;
    const int r1 = min(r0 + kRB, kNodes);
    const int NR = r1 - r0;
    if (NR <= 0) return;
    const int bb = bucket_base[bk];
    const int s1 = bucket_base[bk + 1];
    const int size   = s1 - bb;
    const int staged = min(size, kCap);
    const int tid = threadIdx.x;

    s[tid] = 0;
    s[tid + 256] = 0;
    __syncthreads();

    // stage + count (LDS atomics)
    for (int i = tid; i < staged; i += 256) {
        const int2 p = packed[bb + i];
        st[i] = p;
        atomicAdd(&s[p.x >> 17], 1);
    }
    int2 tail[8];
    int  nt = 0;
    for (int i = kCap + tid; i < size; i += 256) {
        if (nt < 8) {
            tail[nt] = packed[bb + i];
            atomicAdd(&s[tail[nt].x >> 17], 1);
            ++nt;
        }
    }
    __syncthreads();   // all global reads + counts done

    // inclusive scan of s[0..511], 2 elements per thread
    const int i0 = tid, i1 = tid + 256;
#pragma unroll
    for (int off = 1; off < 512; off <<= 1) {
        const int v0 = (i0 >= off) ? s[i0 - off] : 0;
        const int v1 = (i1 >= off) ? s[i1 - off] : 0;
        __syncthreads();
        s[i0] += v0;
        s[i1] += v1;
        __syncthreads();
    }

    // row_start + LDS cursors (exclusive offsets)
    for (int i = tid; i < NR; i += 256) {
        const int excl = i ? s[i - 1] : 0;
        row_start[r0 + i] = bb + excl;
        rcur[i] = excl;
    }
    __syncthreads();

    // scatter to final positions (LDS cursor atomics)
    for (int i = tid; i < staged; i += 256) {
        const int2 p  = st[i];
        const int pos = bb + atomicAdd(&rcur[p.x >> 17], 1);
        packed[pos] = make_int2(p.x & 0x1FFFF, p.y);
    }
#pragma unroll
    for (int t = 0; t < 8; ++t) {
        if (t < nt) {
            const int2 p  = tail[t];
            const int pos = bb + atomicAdd(&rcur[p.x >> 17], 1);
            packed[pos] = make_int2(p.x & 0x1FFFF, p.y);
        }
    }
}

// ---------------------------------------------------------------------------
// Aggregate + ReLU (unchanged): 16 lanes/node, bf16x8 gathers, fp32 acc.
// ---------------------------------------------------------------------------
__global__ __launch_bounds__(256) void gcn_aggregate(const int* __restrict__ row_start,
                                                     const int2* __restrict__ packed,
                                                     const unsigned short* __restrict__ support,
                                                     float* __restrict__ out) {
    const int n  = blockIdx.x * 16 + (threadIdx.x >> 4);
    const int f8 = (threadIdx.x & 15) * 8;
    if (n >= kNodes) return;
    const int s0 = row_start[n];
    const int s1 = row_start[n + 1];
    float acc[8];
#pragma unroll
    for (int j = 0; j < 8; ++j) acc[j] = 0.f;

    int i = s0;
    for (; i + 3 < s1; i += 4) {
        const int2 p0 = packed[i];
        const int2 p1 = packed[i + 1];
        const int2 p2 = packed[i + 2];
        const int2 p3 = packed[i + 3];
        const ush8 a0 = *reinterpret_cast<const ush8*>(support + (size_t)p0.x * kOutF + f8);
        const ush8 a1 = *reinterpret_cast<const ush8*>(support + (size_t)p1.x * kOutF + f8);
        const ush8 a2 = *reinterpret_cast<const ush8*>(support + (size_t)p2.x * kOutF + f8);
        const ush8 a3 = *reinterpret_cast<const ush8*>(support + (size_t)p3.x * kOutF + f8);
        const float v0 = __int_as_float(p0.y), v1 = __int_as_float(p1.y);
        const float v2 = __int_as_float(p2.y), v3 = __int_as_float(p3.y);
#pragma unroll
        for (int j = 0; j < 8; ++j) {
            acc[j] += v0 * bf2f(a0[j]);
            acc[j] += v1 * bf2f(a1[j]);
            acc[j] += v2 * bf2f(a2[j]);
            acc[j] += v3 * bf2f(a3[j]);
        }
    }
    for (; i < s1; ++i) {
        const int2 p = packed[i];
        const float v = __int_as_float(p.y);
        const ush8 a = *reinterpret_cast<const ush8*>(support + (size_t)p.x * kOutF + f8);
#pragma unroll
        for (int j = 0; j < 8; ++j) acc[j] += v * bf2f(a[j]);
    }

    float4 o0 = make_float4(fmaxf(acc[0], 0.f), fmaxf(acc[1], 0.f),
                            fmaxf(acc[2], 0.f), fmaxf(acc[3], 0.f));
    float4 o1 = make_float4(fmaxf(acc[4], 0.f), fmaxf(acc[5], 0.f),
                            fmaxf(acc[6], 0.f), fmaxf(acc[7], 0.f));
    *reinterpret_cast<float4*>(out + (size_t)n * kOutF + f8)     = o0;
    *reinterpret_cast<float4*>(out + (size_t)n * kOutF + f8 + 4) = o1;
}

extern "C" void kernel_launch(void* const* d_in, const int* in_sizes, int n_in,
                              void* d_out, int out_size, void* d_ws, size_t ws_size,
                              hipStream_t stream) {
    const float* x    = (const float*)d_in[0];
    const int*   erow = (const int*)  d_in[1];
    const int*   ecol = (const int*)  d_in[2];
    const float* eval = (const float*)d_in[3];
    const float* W    = (const float*)d_in[4];
    const float* b    = (const float*)d_in[5];
    float* out = (float*)d_out;

    char* ws = (char*)d_ws;
    unsigned short* support = (unsigned short*)(ws);       // 25,600,000 B
    int2* packed        = (int2*)(ws + 25600000);          // 12,800,000 B
    int*  row_start     = (int*) (ws + 38400000);          //    400,004 B
    int*  bucket_tot    = (int*) (ws + 38800008);          //      1,024 B
    int*  bucket_base   = (int*) (ws + 38801032);          //      1,028 B
    int*  bucket_cursor = (int*) (ws + 38802060);          //      1,024 B

    // 1) support = bf16(x@W + b)
    gcn_gemm<<<kGemmBlocks, 256, 0, stream>>>(x, W, b, support);

    // 2) CSR build: bucket hist -> bucket scan -> bin -> per-bucket place
    hipMemsetAsync(bucket_tot, 0, kNB * sizeof(int), stream);
    gcn_bhist<<<1024, 256, 0, stream>>>(erow, bucket_tot);
    gcn_bscan<<<1, 256, 0, stream>>>(bucket_tot, bucket_base, bucket_cursor, row_start);
    gcn_bin  <<<kBucketBlocks, 256, 0, stream>>>(erow, ecol, eval, bucket_cursor, packed);
    gcn_place<<<kNB, 256, 0, stream>>>(bucket_base, row_start, packed);

    // 3) aggregate + relu
    gcn_aggregate<<<(kNodes + 15) / 16, 256, 0, stream>>>(row_start, packed, support, out);
}